// Round 2
// baseline (5454.616 us; speedup 1.0000x reference)
//
#include <hip/hip_runtime.h>
#include <math.h>

#define T_TOKENS 2048
#define H_DIM 2048
#define E_NUM 64
#define I_DIM 768
#define TOPK 8
#define CAP 1024
#define TK (T_TOKENS * TOPK)

__device__ inline unsigned short f2bf(float f) {
    union { float f; unsigned int u; } v; v.f = f;
    return (unsigned short)((v.u + 0x7FFFu + ((v.u >> 16) & 1u)) >> 16);
}

// ---------------- zero output + counts ----------------
__global__ __launch_bounds__(256) void zero_kernel(float* __restrict__ out, int n4, int* __restrict__ cnt) {
    int i = blockIdx.x * 256 + threadIdx.x;
    if (i < n4) reinterpret_cast<float4*>(out)[i] = make_float4(0.f, 0.f, 0.f, 0.f);
    if (blockIdx.x == 0 && threadIdx.x < E_NUM) cnt[threadIdx.x] = 0;
}

// ---------------- router: logits -> top8 (redundant scalar select) -> softmax over top8 ----------------
__global__ __launch_bounds__(256) void router_kernel(const float* __restrict__ x,
                                                     const float* __restrict__ wr,
                                                     int* __restrict__ topi,
                                                     float* __restrict__ topw) {
    __shared__ float xs[H_DIM];
    __shared__ float lg[E_NUM];
    int t = blockIdx.x;
    int tid = threadIdx.x;
    const float* xrow = x + (size_t)t * H_DIM;
    {
        int i = tid * 8;
        *reinterpret_cast<float4*>(xs + i)     = *reinterpret_cast<const float4*>(xrow + i);
        *reinterpret_cast<float4*>(xs + i + 4) = *reinterpret_cast<const float4*>(xrow + i + 4);
    }
    __syncthreads();
    int w = tid >> 6, lane = tid & 63;
    for (int eo = 0; eo < 16; ++eo) {
        int e = w * 16 + eo;
        const float* wrow = wr + (size_t)e * H_DIM;
        float p = 0.f;
        for (int h = lane; h < H_DIM; h += 64) p += xs[h] * wrow[h];
        #pragma unroll
        for (int off = 32; off; off >>= 1) p += __shfl_xor(p, off);
        if (lane == 0) lg[e] = p;
    }
    __syncthreads();
    // Each of lanes 0..7 redundantly computes the full stable top-8
    // (descending value, ascending index on ties) — plain scalar code,
    // no shuffles, no cross-lane LDS ordering assumptions.
    if (tid < TOPK) {
        float pv = 3.4e38f; int pi = -1;
        float m = 0.f, s = 0.f, myv = 0.f; int myi = 0;
        for (int r = 0; r < TOPK; ++r) {
            float best = -3.4e38f; int bi = -1;
            for (int e2 = 0; e2 < E_NUM; ++e2) {
                float v = lg[e2];
                bool excl = (v > pv) || (v == pv && e2 <= pi);
                if (!excl && v > best) { best = v; bi = e2; }
            }
            if (r == 0) m = best;
            s += expf(best - m);
            if (r == tid) { myv = best; myi = bi; }
            pv = best; pi = bi;
        }
        topw[t * TOPK + tid] = expf(myv - m) / s;
        topi[t * TOPK + tid] = myi;
    }
}

// ---------------- dispatch entries to expert slots ----------------
__global__ __launch_bounds__(256) void dispatch_kernel(const int* __restrict__ topi,
                                                       int* __restrict__ cnt,
                                                       int* __restrict__ slot) {
    int i = blockIdx.x * 256 + threadIdx.x;
    int e = topi[i];
    int pos = atomicAdd(cnt + e, 1);
    if (pos < CAP) slot[e * CAP + pos] = i;
}

// ---------------- exclusive prefix of clamped counts ----------------
__global__ void offs_kernel(const int* __restrict__ cnt, int* __restrict__ offs) {
    if (threadIdx.x == 0) {
        int run = 0;
        for (int e = 0; e < E_NUM; ++e) {
            offs[e] = run;
            int c = cnt[e]; if (c > CAP) c = CAP;
            run += c;
        }
    }
}

// ---------------- GEMM A (pure fp32 VALU): h = silu(x@Wg) * (x@Wu) -> bf16 ws ----------------
// block: 64 rows x 64 I-cols (gate+up pair). thread: 4 rows x 4 cols, accg+accu.
__global__ __launch_bounds__(256) void gu_f32_kernel(const float* __restrict__ x,
                                                     const float* __restrict__ gup,
                                                     const int* __restrict__ slot,
                                                     const int* __restrict__ cnt,
                                                     const int* __restrict__ offs,
                                                     unsigned short* __restrict__ hws) {
    int e = blockIdx.z;
    int rows = min(cnt[e], CAP);
    int row0 = blockIdx.x * 64;
    if (row0 >= rows) return;
    int c0 = blockIdx.y * 64;

    __shared__ float As[64][36];   // 64 rows x 32 k (+4 pad, 16B-aligned rows)
    __shared__ float Bg[32][68];   // 32 k x 64 gate cols (+4 pad)
    __shared__ float Bu[32][68];   // 32 k x 64 up   cols

    int tid = threadIdx.x;
    int tr = tid >> 4, tc = tid & 15;

    float accg[4][4], accu[4][4];
    #pragma unroll
    for (int i = 0; i < 4; ++i)
        #pragma unroll
        for (int j = 0; j < 4; ++j) { accg[i][j] = 0.f; accu[i][j] = 0.f; }

    // A staging map: 4 threads per row, 8 floats each
    int ar = tid >> 2, aq = tid & 3;
    int arow = row0 + ar;
    int ent = (arow < rows) ? slot[e * CAP + arow] : slot[e * CAP];
    const float* asrc = x + (size_t)(ent >> 3) * H_DIM + aq * 8;

    // B staging map: thread -> (k row, 8-col strip) for both gate and up
    int bk = tid >> 3, bc = (tid & 7) * 8;
    const float* gbase = gup + ((size_t)e * H_DIM + bk) * (2 * I_DIM) + c0 + bc;
    const float* ubase = gbase + I_DIM;

    for (int kk = 0; kk < H_DIM; kk += 32) {
        __syncthreads();
        float4 a0 = *reinterpret_cast<const float4*>(asrc + kk);
        float4 a1 = *reinterpret_cast<const float4*>(asrc + kk + 4);
        *reinterpret_cast<float4*>(&As[ar][aq * 8])     = a0;
        *reinterpret_cast<float4*>(&As[ar][aq * 8 + 4]) = a1;
        const float* gr = gbase + (size_t)kk * (2 * I_DIM);
        const float* ur = ubase + (size_t)kk * (2 * I_DIM);
        float4 g0 = *reinterpret_cast<const float4*>(gr);
        float4 g1 = *reinterpret_cast<const float4*>(gr + 4);
        float4 u0 = *reinterpret_cast<const float4*>(ur);
        float4 u1 = *reinterpret_cast<const float4*>(ur + 4);
        *reinterpret_cast<float4*>(&Bg[bk][bc])     = g0;
        *reinterpret_cast<float4*>(&Bg[bk][bc + 4]) = g1;
        *reinterpret_cast<float4*>(&Bu[bk][bc])     = u0;
        *reinterpret_cast<float4*>(&Bu[bk][bc + 4]) = u1;
        __syncthreads();
        #pragma unroll 4
        for (int k = 0; k < 32; ++k) {
            float av[4];
            #pragma unroll
            for (int i = 0; i < 4; ++i) av[i] = As[tr * 4 + i][k];
            float4 bg = *reinterpret_cast<const float4*>(&Bg[k][tc * 4]);
            float4 bu = *reinterpret_cast<const float4*>(&Bu[k][tc * 4]);
            #pragma unroll
            for (int i = 0; i < 4; ++i) {
                accg[i][0] += av[i] * bg.x; accg[i][1] += av[i] * bg.y;
                accg[i][2] += av[i] * bg.z; accg[i][3] += av[i] * bg.w;
                accu[i][0] += av[i] * bu.x; accu[i][1] += av[i] * bu.y;
                accu[i][2] += av[i] * bu.z; accu[i][3] += av[i] * bu.w;
            }
        }
    }

    int off_e = offs[e];
    #pragma unroll
    for (int i = 0; i < 4; ++i) {
        int row = row0 + tr * 4 + i;
        if (row < rows) {
            unsigned short* hrow = hws + (size_t)(off_e + row) * I_DIM + c0 + tc * 4;
            #pragma unroll
            for (int j = 0; j < 4; ++j) {
                float g = accg[i][j], u = accu[i][j];
                float hv = (g / (1.f + expf(-g))) * u;
                hrow[j] = f2bf(hv);
            }
        }
    }
}

// ---------------- GEMM B (pure fp32 VALU): y += w * (h @ Wd), scatter-add ----------------
__global__ __launch_bounds__(256) void down_f32_kernel(const unsigned short* __restrict__ hws,
                                                       const float* __restrict__ dwn,
                                                       const int* __restrict__ slot,
                                                       const int* __restrict__ cnt,
                                                       const int* __restrict__ offs,
                                                       const float* __restrict__ topw,
                                                       float* __restrict__ out) {
    int e = blockIdx.z;
    int rows = min(cnt[e], CAP);
    int row0 = blockIdx.x * 64;
    if (row0 >= rows) return;
    int c0 = blockIdx.y * 64;

    __shared__ float As[64][36];
    __shared__ float Bs[32][68];

    int tid = threadIdx.x;
    int tr = tid >> 4, tc = tid & 15;

    float acc[4][4];
    #pragma unroll
    for (int i = 0; i < 4; ++i)
        #pragma unroll
        for (int j = 0; j < 4; ++j) acc[i][j] = 0.f;

    int ar = tid >> 2, aq = tid & 3;
    int arow = row0 + ar;
    bool aval = arow < rows;
    int off_e = offs[e];
    const unsigned short* asrc = hws + (size_t)(off_e + (aval ? arow : 0)) * I_DIM + aq * 8;

    int bk = tid >> 3, bc = (tid & 7) * 8;
    const float* wbase = dwn + ((size_t)e * I_DIM + bk) * H_DIM + c0 + bc;

    for (int kk = 0; kk < I_DIM; kk += 32) {
        __syncthreads();
        int4 av = *reinterpret_cast<const int4*>(asrc + kk);  // 8 bf16
        const unsigned short* ap = reinterpret_cast<const unsigned short*>(&av);
        #pragma unroll
        for (int q = 0; q < 8; ++q)
            As[ar][aq * 8 + q] = __uint_as_float(((unsigned int)ap[q]) << 16);
        const float* wrow = wbase + (size_t)kk * H_DIM;
        float4 w0 = *reinterpret_cast<const float4*>(wrow);
        float4 w1 = *reinterpret_cast<const float4*>(wrow + 4);
        *reinterpret_cast<float4*>(&Bs[bk][bc])     = w0;
        *reinterpret_cast<float4*>(&Bs[bk][bc + 4]) = w1;
        __syncthreads();
        #pragma unroll 4
        for (int k = 0; k < 32; ++k) {
            float av4[4];
            #pragma unroll
            for (int i = 0; i < 4; ++i) av4[i] = As[tr * 4 + i][k];
            float4 b = *reinterpret_cast<const float4*>(&Bs[k][tc * 4]);
            #pragma unroll
            for (int i = 0; i < 4; ++i) {
                acc[i][0] += av4[i] * b.x; acc[i][1] += av4[i] * b.y;
                acc[i][2] += av4[i] * b.z; acc[i][3] += av4[i] * b.w;
            }
        }
    }

    #pragma unroll
    for (int i = 0; i < 4; ++i) {
        int row = row0 + tr * 4 + i;
        if (row < rows) {
            int ent2 = slot[e * CAP + row];
            float wgt = topw[ent2];
            float* obase = out + (size_t)(ent2 >> 3) * H_DIM + c0 + tc * 4;
            #pragma unroll
            for (int j = 0; j < 4; ++j)
                atomicAdd(obase + j, wgt * acc[i][j]);
        }
    }
}

extern "C" void kernel_launch(void* const* d_in, const int* in_sizes, int n_in,
                              void* d_out, int out_size, void* d_ws, size_t ws_size,
                              hipStream_t stream) {
    const float* x   = (const float*)d_in[0];
    const float* wr  = (const float*)d_in[1];
    const float* gup = (const float*)d_in[2];
    const float* dwn = (const float*)d_in[3];
    float* out = (float*)d_out;
    char* ws = (char*)d_ws;

    int*            topi = (int*)(ws + 0);         //  64 KB
    float*          topw = (float*)(ws + 65536);   //  64 KB
    int*            cnt  = (int*)(ws + 131072);    // 256 B
    int*            offs = (int*)(ws + 131328);    // 256 B
    int*            slot = (int*)(ws + 131584);    // 256 KB
    unsigned short* hws  = (unsigned short*)(ws + 393728);  // 24 MB
    // total ws usage: ~24.4 MB

    int n4 = out_size / 4;
    zero_kernel<<<(n4 + 255) / 256, 256, 0, stream>>>(out, n4, cnt);
    router_kernel<<<T_TOKENS, 256, 0, stream>>>(x, wr, topi, topw);
    dispatch_kernel<<<TK / 256, 256, 0, stream>>>(topi, cnt, slot);
    offs_kernel<<<1, 64, 0, stream>>>(cnt, offs);
    gu_f32_kernel<<<dim3(16, 12, E_NUM), 256, 0, stream>>>(x, gup, slot, cnt, offs, hws);
    down_f32_kernel<<<dim3(16, 32, E_NUM), 256, 0, stream>>>(hws, dwn, slot, cnt, offs, topw, out);
}

// Round 3
// 3379.351 us; speedup vs baseline: 1.6141x; 1.6141x over previous
//
#include <hip/hip_runtime.h>
#include <math.h>

#define T_TOKENS 2048
#define H_DIM 2048
#define E_NUM 64
#define I_DIM 768
#define TOPK 8
#define CAP 1024
#define TK (T_TOKENS * TOPK)

typedef __attribute__((ext_vector_type(8))) short s8v;
typedef __attribute__((ext_vector_type(4))) float f32x4;

__device__ inline unsigned short f2bf(float f) {
    union { float f; unsigned int u; } v; v.f = f;
    return (unsigned short)((v.u + 0x7FFFu + ((v.u >> 16) & 1u)) >> 16);
}
__device__ inline unsigned int pack2(float a, float b) {
    return (unsigned)f2bf(a) | ((unsigned)f2bf(b) << 16);
}

// ---------------- zero output + counts ----------------
__global__ __launch_bounds__(256) void zero_kernel(float* __restrict__ out, int n4, int* __restrict__ cnt) {
    int i = blockIdx.x * 256 + threadIdx.x;
    if (i < n4) reinterpret_cast<float4*>(out)[i] = make_float4(0.f, 0.f, 0.f, 0.f);
    if (blockIdx.x == 0 && threadIdx.x < E_NUM) cnt[threadIdx.x] = 0;
}

// ---------------- router (proven in round 2) ----------------
__global__ __launch_bounds__(256) void router_kernel(const float* __restrict__ x,
                                                     const float* __restrict__ wr,
                                                     int* __restrict__ topi,
                                                     float* __restrict__ topw) {
    __shared__ float xs[H_DIM];
    __shared__ float lg[E_NUM];
    int t = blockIdx.x;
    int tid = threadIdx.x;
    const float* xrow = x + (size_t)t * H_DIM;
    {
        int i = tid * 8;
        *reinterpret_cast<float4*>(xs + i)     = *reinterpret_cast<const float4*>(xrow + i);
        *reinterpret_cast<float4*>(xs + i + 4) = *reinterpret_cast<const float4*>(xrow + i + 4);
    }
    __syncthreads();
    int w = tid >> 6, lane = tid & 63;
    for (int eo = 0; eo < 16; ++eo) {
        int e = w * 16 + eo;
        const float* wrow = wr + (size_t)e * H_DIM;
        float p = 0.f;
        for (int h = lane; h < H_DIM; h += 64) p += xs[h] * wrow[h];
        #pragma unroll
        for (int off = 32; off; off >>= 1) p += __shfl_xor(p, off);
        if (lane == 0) lg[e] = p;
    }
    __syncthreads();
    if (tid < TOPK) {
        float pv = 3.4e38f; int pi = -1;
        float m = 0.f, s = 0.f, myv = 0.f; int myi = 0;
        for (int r = 0; r < TOPK; ++r) {
            float best = -3.4e38f; int bi = -1;
            for (int e2 = 0; e2 < E_NUM; ++e2) {
                float v = lg[e2];
                bool excl = (v > pv) || (v == pv && e2 <= pi);
                if (!excl && v > best) { best = v; bi = e2; }
            }
            if (r == 0) m = best;
            s += expf(best - m);
            if (r == tid) { myv = best; myi = bi; }
            pv = best; pi = bi;
        }
        topw[t * TOPK + tid] = expf(myv - m) / s;
        topi[t * TOPK + tid] = myi;
    }
}

// ---------------- dispatch entries to expert slots ----------------
__global__ __launch_bounds__(256) void dispatch_kernel(const int* __restrict__ topi,
                                                       int* __restrict__ cnt,
                                                       int* __restrict__ slot) {
    int i = blockIdx.x * 256 + threadIdx.x;
    int e = topi[i];
    int pos = atomicAdd(cnt + e, 1);
    if (pos < CAP) slot[e * CAP + pos] = i;
}

// ---------------- exclusive prefix of clamped counts ----------------
__global__ void offs_kernel(const int* __restrict__ cnt, int* __restrict__ offs) {
    if (threadIdx.x == 0) {
        int run = 0;
        for (int e = 0; e < E_NUM; ++e) {
            offs[e] = run;
            int c = cnt[e]; if (c > CAP) c = CAP;
            run += c;
        }
    }
}

// ---------------- GEMM A (MFMA): h = silu(x@Wg) * (x@Wu) -> bf16 ws ----------------
// 64 rows x 64 I-cols (gate+up), A staged from fp32 x with in-reg f2bf.
__global__ __launch_bounds__(256) void gemm_gu_kernel(const float* __restrict__ x,
                                                      const float* __restrict__ gup,
                                                      const int* __restrict__ slot,
                                                      const int* __restrict__ cnt,
                                                      const int* __restrict__ offs,
                                                      unsigned short* __restrict__ hws) {
    int e = blockIdx.z;
    int rows = min(cnt[e], CAP);
    int row0 = blockIdx.x * 64;
    if (row0 >= rows) return;
    int c0 = blockIdx.y * 64;

    __shared__ unsigned short As[64][40];   // 32 k + 8 pad
    __shared__ unsigned short Bt[128][40];  // [col][k]: 64 gate + 64 up

    int tid = threadIdx.x;
    int w = tid >> 6, lane = tid & 63, grp = lane >> 4, l15 = lane & 15;

    // A staging: 4 threads/row, 8 elements each (fp32 -> bf16)
    int ar = tid >> 2, aq = tid & 3;
    int arow = row0 + ar;
    int ent = (arow < rows) ? slot[e * CAP + arow] : slot[e * CAP];
    const float* asrc = x + (size_t)(ent >> 3) * H_DIM + aq * 8;

    // B staging: thread -> (k row, 16-col strip)
    int bk = tid >> 3, cb = (tid & 7) * 16;
    const float* wbase = gup + ((size_t)e * H_DIM + bk) * (2 * I_DIM);

    f32x4 zero4 = {0.f, 0.f, 0.f, 0.f};
    f32x4 acc[8];
    #pragma unroll
    for (int f = 0; f < 8; ++f) acc[f] = zero4;

    for (int kk = 0; kk < H_DIM; kk += 32) {
        __syncthreads();
        float4 a0 = *reinterpret_cast<const float4*>(asrc + kk);
        float4 a1 = *reinterpret_cast<const float4*>(asrc + kk + 4);
        int4 ao;
        ao.x = (int)pack2(a0.x, a0.y);
        ao.y = (int)pack2(a0.z, a0.w);
        ao.z = (int)pack2(a1.x, a1.y);
        ao.w = (int)pack2(a1.z, a1.w);
        *reinterpret_cast<int4*>(&As[ar][aq * 8]) = ao;
        const float* wrow = wbase + (size_t)kk * (2 * I_DIM);
        #pragma unroll
        for (int j = 0; j < 4; ++j) {
            int cl = cb + j * 4;
            int col = (cl < 64) ? (c0 + cl) : (I_DIM + c0 + (cl - 64));
            float4 wv = *reinterpret_cast<const float4*>(wrow + col);
            Bt[cl + 0][bk] = f2bf(wv.x);
            Bt[cl + 1][bk] = f2bf(wv.y);
            Bt[cl + 2][bk] = f2bf(wv.z);
            Bt[cl + 3][bk] = f2bf(wv.w);
        }
        __syncthreads();
        s8v a = *reinterpret_cast<const s8v*>(&As[w * 16 + l15][grp * 8]);
        #pragma unroll
        for (int f = 0; f < 8; ++f) {
            s8v b = *reinterpret_cast<const s8v*>(&Bt[f * 16 + l15][grp * 8]);
            acc[f] = __builtin_amdgcn_mfma_f32_16x16x32_bf16(a, b, acc[f], 0, 0, 0);
        }
    }

    int off_e = offs[e];
    #pragma unroll
    for (int f = 0; f < 4; ++f) {
        #pragma unroll
        for (int r = 0; r < 4; ++r) {
            int row = row0 + w * 16 + grp * 4 + r;
            if (row < rows) {
                float g = acc[f][r];
                float u = acc[f + 4][r];
                float hv = (g / (1.f + expf(-g))) * u;
                hws[(size_t)(off_e + row) * I_DIM + (c0 + f * 16 + l15)] = f2bf(hv);
            }
        }
    }
}

// ---------------- GEMM B (MFMA): y += w * (h @ Wd), scatter-add ----------------
__global__ __launch_bounds__(256) void gemm_down_kernel(const unsigned short* __restrict__ hws,
                                                        const float* __restrict__ dwn,
                                                        const int* __restrict__ slot,
                                                        const int* __restrict__ cnt,
                                                        const int* __restrict__ offs,
                                                        const float* __restrict__ topw,
                                                        float* __restrict__ out) {
    int e = blockIdx.z;
    int rows = min(cnt[e], CAP);
    int row0 = blockIdx.x * 64;
    if (row0 >= rows) return;
    int c0 = blockIdx.y * 64;

    __shared__ unsigned short As[64][40];
    __shared__ unsigned short Bt[64][40];

    int tid = threadIdx.x;
    int w = tid >> 6, lane = tid & 63, grp = lane >> 4, l15 = lane & 15;

    int ar = tid >> 2, aq = tid & 3;
    int arow = row0 + ar;
    bool aval = (arow < rows);
    int off_e = offs[e];
    const unsigned short* asrc = hws + (size_t)(off_e + (aval ? arow : 0)) * I_DIM + aq * 8;

    int bk = tid >> 3, cb = (tid & 7) * 8;
    const float* wbase = dwn + ((size_t)e * I_DIM + bk) * H_DIM + c0 + cb;

    f32x4 zero4 = {0.f, 0.f, 0.f, 0.f};
    f32x4 acc[4];
    #pragma unroll
    for (int f = 0; f < 4; ++f) acc[f] = zero4;

    for (int kk = 0; kk < I_DIM; kk += 32) {
        __syncthreads();
        int4 av = *reinterpret_cast<const int4*>(asrc + kk);
        *reinterpret_cast<int4*>(&As[ar][aq * 8]) = av;
        const float* wrow = wbase + (size_t)kk * H_DIM;
        float4 w0 = *reinterpret_cast<const float4*>(wrow);
        float4 w1 = *reinterpret_cast<const float4*>(wrow + 4);
        Bt[cb + 0][bk] = f2bf(w0.x);
        Bt[cb + 1][bk] = f2bf(w0.y);
        Bt[cb + 2][bk] = f2bf(w0.z);
        Bt[cb + 3][bk] = f2bf(w0.w);
        Bt[cb + 4][bk] = f2bf(w1.x);
        Bt[cb + 5][bk] = f2bf(w1.y);
        Bt[cb + 6][bk] = f2bf(w1.z);
        Bt[cb + 7][bk] = f2bf(w1.w);
        __syncthreads();
        s8v a = *reinterpret_cast<const s8v*>(&As[w * 16 + l15][grp * 8]);
        #pragma unroll
        for (int f = 0; f < 4; ++f) {
            s8v b = *reinterpret_cast<const s8v*>(&Bt[f * 16 + l15][grp * 8]);
            acc[f] = __builtin_amdgcn_mfma_f32_16x16x32_bf16(a, b, acc[f], 0, 0, 0);
        }
    }

    #pragma unroll
    for (int r = 0; r < 4; ++r) {
        int row = row0 + w * 16 + grp * 4 + r;
        if (row < rows) {
            int ent2 = slot[e * CAP + row];
            int t = ent2 >> 3;
            float wgt = topw[ent2];
            float* obase = out + (size_t)t * H_DIM + c0 + l15;
            #pragma unroll
            for (int f = 0; f < 4; ++f)
                atomicAdd(obase + f * 16, wgt * acc[f][r]);
        }
    }
}

extern "C" void kernel_launch(void* const* d_in, const int* in_sizes, int n_in,
                              void* d_out, int out_size, void* d_ws, size_t ws_size,
                              hipStream_t stream) {
    const float* x   = (const float*)d_in[0];
    const float* wr  = (const float*)d_in[1];
    const float* gup = (const float*)d_in[2];
    const float* dwn = (const float*)d_in[3];
    float* out = (float*)d_out;
    char* ws = (char*)d_ws;

    int*            topi = (int*)(ws + 0);         //  64 KB
    float*          topw = (float*)(ws + 65536);   //  64 KB
    int*            cnt  = (int*)(ws + 131072);    // 256 B
    int*            offs = (int*)(ws + 131328);    // 256 B
    int*            slot = (int*)(ws + 131584);    // 256 KB
    unsigned short* hws  = (unsigned short*)(ws + 393728);  // 24 MB
    // total ws usage: ~25.6 MB (== round-2 proven footprint)

    int n4 = out_size / 4;
    zero_kernel<<<(n4 + 255) / 256, 256, 0, stream>>>(out, n4, cnt);
    router_kernel<<<T_TOKENS, 256, 0, stream>>>(x, wr, topi, topw);
    dispatch_kernel<<<TK / 256, 256, 0, stream>>>(topi, cnt, slot);
    offs_kernel<<<1, 64, 0, stream>>>(cnt, offs);
    gemm_gu_kernel<<<dim3(16, 12, E_NUM), 256, 0, stream>>>(x, gup, slot, cnt, offs, hws);
    gemm_down_kernel<<<dim3(16, 32, E_NUM), 256, 0, stream>>>(hws, dwn, slot, cnt, offs, topw, out);
}

// Round 4
// 1411.576 us; speedup vs baseline: 3.8642x; 2.3940x over previous
//
#include <hip/hip_runtime.h>
#include <math.h>

#define T_TOKENS 2048
#define H_DIM 2048
#define E_NUM 64
#define I_DIM 768
#define TOPK 8
#define CAP 1024
#define TK (T_TOKENS * TOPK)
#define RCH 384   // rows per super-chunk (6 x 64)
#define NCHMAX 6

typedef __attribute__((ext_vector_type(8))) short s8v;
typedef __attribute__((ext_vector_type(4))) float f32x4;

__device__ inline unsigned short f2bf(float f) {
    union { float f; unsigned int u; } v; v.f = f;
    return (unsigned short)((v.u + 0x7FFFu + ((v.u >> 16) & 1u)) >> 16);
}
__device__ inline unsigned int pack2(float a, float b) {
    return (unsigned)f2bf(a) | ((unsigned)f2bf(b) << 16);
}

// ---------------- zero output + counts ----------------
__global__ __launch_bounds__(256) void zero_kernel(float* __restrict__ out, int n4, int* __restrict__ cnt) {
    int i = blockIdx.x * 256 + threadIdx.x;
    if (i < n4) reinterpret_cast<float4*>(out)[i] = make_float4(0.f, 0.f, 0.f, 0.f);
    if (blockIdx.x == 0 && threadIdx.x < E_NUM) cnt[threadIdx.x] = 0;
}

// ---------------- router (proven) ----------------
__global__ __launch_bounds__(256) void router_kernel(const float* __restrict__ x,
                                                     const float* __restrict__ wr,
                                                     int* __restrict__ topi,
                                                     float* __restrict__ topw) {
    __shared__ float xs[H_DIM];
    __shared__ float lg[E_NUM];
    int t = blockIdx.x;
    int tid = threadIdx.x;
    const float* xrow = x + (size_t)t * H_DIM;
    {
        int i = tid * 8;
        *reinterpret_cast<float4*>(xs + i)     = *reinterpret_cast<const float4*>(xrow + i);
        *reinterpret_cast<float4*>(xs + i + 4) = *reinterpret_cast<const float4*>(xrow + i + 4);
    }
    __syncthreads();
    int w = tid >> 6, lane = tid & 63;
    for (int eo = 0; eo < 16; ++eo) {
        int e = w * 16 + eo;
        const float* wrow = wr + (size_t)e * H_DIM;
        float p = 0.f;
        for (int h = lane; h < H_DIM; h += 64) p += xs[h] * wrow[h];
        #pragma unroll
        for (int off = 32; off; off >>= 1) p += __shfl_xor(p, off);
        if (lane == 0) lg[e] = p;
    }
    __syncthreads();
    if (tid < TOPK) {
        float pv = 3.4e38f; int pi = -1;
        float m = 0.f, s = 0.f, myv = 0.f; int myi = 0;
        for (int r = 0; r < TOPK; ++r) {
            float best = -3.4e38f; int bi = -1;
            for (int e2 = 0; e2 < E_NUM; ++e2) {
                float v = lg[e2];
                bool excl = (v > pv) || (v == pv && e2 <= pi);
                if (!excl && v > best) { best = v; bi = e2; }
            }
            if (r == 0) m = best;
            s += expf(best - m);
            if (r == tid) { myv = best; myi = bi; }
            pv = best; pi = bi;
        }
        topw[t * TOPK + tid] = expf(myv - m) / s;
        topi[t * TOPK + tid] = myi;
    }
}

// ---------------- dispatch entries to expert slots ----------------
__global__ __launch_bounds__(256) void dispatch_kernel(const int* __restrict__ topi,
                                                       int* __restrict__ cnt,
                                                       int* __restrict__ slot) {
    int i = blockIdx.x * 256 + threadIdx.x;
    int e = topi[i];
    int pos = atomicAdd(cnt + e, 1);
    if (pos < CAP) slot[e * CAP + pos] = i;
}

// ---------------- exclusive prefix of clamped counts ----------------
__global__ void offs_kernel(const int* __restrict__ cnt, int* __restrict__ offs) {
    if (threadIdx.x == 0) {
        int run = 0;
        for (int e = 0; e < E_NUM; ++e) {
            offs[e] = run;
            int c = cnt[e]; if (c > CAP) c = CAP;
            run += c;
        }
    }
}

// ---------------- GEMM A (MFMA): h = silu(x@Wg)*(x@Wu) -> bf16 ws ----------------
// block = (super-chunk s, 32-col strip of I, expert). Up to 384 rows per block.
__global__ __launch_bounds__(256) void gemm_gu_kernel(const float* __restrict__ x,
                                                      const float* __restrict__ gup,
                                                      const int* __restrict__ slot,
                                                      const int* __restrict__ cnt,
                                                      const int* __restrict__ offs,
                                                      unsigned short* __restrict__ hws) {
    int e = blockIdx.z;
    int rows = min(cnt[e], CAP);
    int r0 = blockIdx.x * RCH;
    if (r0 >= rows) return;
    int rrem = rows - r0;
    int nch = min(NCHMAX, (rrem + 63) >> 6);
    int c0g = blockIdx.y * 32;

    __shared__ unsigned short As[RCH][40];  // [row][k32 + pad8]
    __shared__ unsigned short Bt[64][40];   // [colL][k32 + pad8]; L<32 gate, L>=32 up

    int tid = threadIdx.x;
    int w = tid >> 6, lane = tid & 63, grp = lane >> 4, l15 = lane & 15;

    // A staging: pass p handles row_local = (tid>>2) + p*64, quarter aq
    int arow_l = tid >> 2, aq = tid & 3;
    const float* abase0; const float* abase1; const float* abase2;
    const float* abase3; const float* abase4; const float* abase5;
    {
        int ent0 = slot[e * CAP + r0];
        #pragma unroll
        for (int p = 0; p < NCHMAX; ++p) {
            int rg = r0 + arow_l + p * 64;
            int ent = (rg < rows) ? slot[e * CAP + rg] : ent0;
            const float* bp = x + (size_t)(ent >> 3) * H_DIM + aq * 8;
            if (p == 0) abase0 = bp; else if (p == 1) abase1 = bp;
            else if (p == 2) abase2 = bp; else if (p == 3) abase3 = bp;
            else if (p == 4) abase4 = bp; else abase5 = bp;
        }
    }

    // B staging: thread owns (colL = tid&63, k-oct = tid>>6)
    int bL = tid & 63, boct = tid >> 6;
    int gcol = (bL < 32) ? (c0g + bL) : (I_DIM + c0g + (bL - 32));
    const float* bbase = gup + ((size_t)e * H_DIM + boct * 8) * (2 * I_DIM) + gcol;

    f32x4 zero4 = {0.f, 0.f, 0.f, 0.f};
    f32x4 acc[NCHMAX][4];
    #pragma unroll
    for (int c = 0; c < NCHMAX; ++c)
        #pragma unroll
        for (int f = 0; f < 4; ++f) acc[c][f] = zero4;

    for (int kk = 0; kk < H_DIM; kk += 32) {
        __syncthreads();
        // B: 8 strided-dword loads (coalesced across lanes), pack, one b128 write
        float bv[8];
        #pragma unroll
        for (int j = 0; j < 8; ++j) bv[j] = bbase[(size_t)(kk + j) * (2 * I_DIM)];
        int4 bo;
        bo.x = (int)pack2(bv[0], bv[1]);
        bo.y = (int)pack2(bv[2], bv[3]);
        bo.z = (int)pack2(bv[4], bv[5]);
        bo.w = (int)pack2(bv[6], bv[7]);
        *reinterpret_cast<int4*>(&Bt[bL][boct * 8]) = bo;
        // A: per active chunk, 2 float4 loads + pack + one b128 write
        #pragma unroll
        for (int p = 0; p < NCHMAX; ++p) {
            if (p < nch) {
                const float* ap = (p == 0) ? abase0 : (p == 1) ? abase1 : (p == 2) ? abase2
                                : (p == 3) ? abase3 : (p == 4) ? abase4 : abase5;
                float4 a0 = *reinterpret_cast<const float4*>(ap + kk);
                float4 a1 = *reinterpret_cast<const float4*>(ap + kk + 4);
                int4 ao;
                ao.x = (int)pack2(a0.x, a0.y);
                ao.y = (int)pack2(a0.z, a0.w);
                ao.z = (int)pack2(a1.x, a1.y);
                ao.w = (int)pack2(a1.z, a1.w);
                *reinterpret_cast<int4*>(&As[arow_l + p * 64][aq * 8]) = ao;
            }
        }
        __syncthreads();
        s8v b0 = *reinterpret_cast<const s8v*>(&Bt[0 * 16 + l15][grp * 8]);
        s8v b1 = *reinterpret_cast<const s8v*>(&Bt[1 * 16 + l15][grp * 8]);
        s8v b2 = *reinterpret_cast<const s8v*>(&Bt[2 * 16 + l15][grp * 8]);
        s8v b3 = *reinterpret_cast<const s8v*>(&Bt[3 * 16 + l15][grp * 8]);
        #pragma unroll
        for (int ch = 0; ch < NCHMAX; ++ch) {
            if (ch < nch) {
                s8v a = *reinterpret_cast<const s8v*>(&As[ch * 64 + w * 16 + l15][grp * 8]);
                acc[ch][0] = __builtin_amdgcn_mfma_f32_16x16x32_bf16(a, b0, acc[ch][0], 0, 0, 0);
                acc[ch][1] = __builtin_amdgcn_mfma_f32_16x16x32_bf16(a, b1, acc[ch][1], 0, 0, 0);
                acc[ch][2] = __builtin_amdgcn_mfma_f32_16x16x32_bf16(a, b2, acc[ch][2], 0, 0, 0);
                acc[ch][3] = __builtin_amdgcn_mfma_f32_16x16x32_bf16(a, b3, acc[ch][3], 0, 0, 0);
            }
        }
    }

    int off_e = offs[e];
    #pragma unroll
    for (int ch = 0; ch < NCHMAX; ++ch) {
        if (ch < nch) {
            #pragma unroll
            for (int f = 0; f < 2; ++f) {
                #pragma unroll
                for (int r = 0; r < 4; ++r) {
                    int rg = r0 + ch * 64 + w * 16 + grp * 4 + r;
                    if (rg < rows) {
                        float g = acc[ch][f][r];
                        float u = acc[ch][f + 2][r];
                        float hv = (g / (1.f + expf(-g))) * u;
                        hws[(size_t)(off_e + rg) * I_DIM + (c0g + f * 16 + l15)] = f2bf(hv);
                    }
                }
            }
        }
    }
}

// ---------------- GEMM B (MFMA): y += w * (h @ Wd), scatter-add ----------------
__global__ __launch_bounds__(256) void gemm_down_kernel(const unsigned short* __restrict__ hws,
                                                        const float* __restrict__ dwn,
                                                        const int* __restrict__ slot,
                                                        const int* __restrict__ cnt,
                                                        const int* __restrict__ offs,
                                                        const float* __restrict__ topw,
                                                        float* __restrict__ out) {
    int e = blockIdx.z;
    int rows = min(cnt[e], CAP);
    int r0 = blockIdx.x * RCH;
    if (r0 >= rows) return;
    int rrem = rows - r0;
    int nch = min(NCHMAX, (rrem + 63) >> 6);
    int c0 = blockIdx.y * 64;
    int off_e = offs[e];

    __shared__ unsigned short As[RCH][40];
    __shared__ unsigned short Bt[64][40];

    int tid = threadIdx.x;
    int w = tid >> 6, lane = tid & 63, grp = lane >> 4, l15 = lane & 15;

    int arow_l = tid >> 2, aq = tid & 3;
    const unsigned short* abase0; const unsigned short* abase1; const unsigned short* abase2;
    const unsigned short* abase3; const unsigned short* abase4; const unsigned short* abase5;
    #pragma unroll
    for (int p = 0; p < NCHMAX; ++p) {
        int rl = arow_l + p * 64;
        int rg = r0 + rl;
        int rc = (rg < rows) ? rg : r0;
        const unsigned short* bp = hws + (size_t)(off_e + rc) * I_DIM + aq * 8;
        if (p == 0) abase0 = bp; else if (p == 1) abase1 = bp;
        else if (p == 2) abase2 = bp; else if (p == 3) abase3 = bp;
        else if (p == 4) abase4 = bp; else abase5 = bp;
    }

    int bL = tid & 63, boct = tid >> 6;
    const float* bbase = dwn + ((size_t)e * I_DIM + boct * 8) * H_DIM + c0 + bL;

    f32x4 zero4 = {0.f, 0.f, 0.f, 0.f};
    f32x4 acc[NCHMAX][4];
    #pragma unroll
    for (int c = 0; c < NCHMAX; ++c)
        #pragma unroll
        for (int f = 0; f < 4; ++f) acc[c][f] = zero4;

    for (int kk = 0; kk < I_DIM; kk += 32) {
        __syncthreads();
        float bv[8];
        #pragma unroll
        for (int j = 0; j < 8; ++j) bv[j] = bbase[(size_t)(kk + j) * H_DIM];
        int4 bo;
        bo.x = (int)pack2(bv[0], bv[1]);
        bo.y = (int)pack2(bv[2], bv[3]);
        bo.z = (int)pack2(bv[4], bv[5]);
        bo.w = (int)pack2(bv[6], bv[7]);
        *reinterpret_cast<int4*>(&Bt[bL][boct * 8]) = bo;
        #pragma unroll
        for (int p = 0; p < NCHMAX; ++p) {
            if (p < nch) {
                const unsigned short* ap = (p == 0) ? abase0 : (p == 1) ? abase1 : (p == 2) ? abase2
                                         : (p == 3) ? abase3 : (p == 4) ? abase4 : abase5;
                int4 av = *reinterpret_cast<const int4*>(ap + kk);
                *reinterpret_cast<int4*>(&As[arow_l + p * 64][aq * 8]) = av;
            }
        }
        __syncthreads();
        s8v b0 = *reinterpret_cast<const s8v*>(&Bt[0 * 16 + l15][grp * 8]);
        s8v b1 = *reinterpret_cast<const s8v*>(&Bt[1 * 16 + l15][grp * 8]);
        s8v b2 = *reinterpret_cast<const s8v*>(&Bt[2 * 16 + l15][grp * 8]);
        s8v b3 = *reinterpret_cast<const s8v*>(&Bt[3 * 16 + l15][grp * 8]);
        #pragma unroll
        for (int ch = 0; ch < NCHMAX; ++ch) {
            if (ch < nch) {
                s8v a = *reinterpret_cast<const s8v*>(&As[ch * 64 + w * 16 + l15][grp * 8]);
                acc[ch][0] = __builtin_amdgcn_mfma_f32_16x16x32_bf16(a, b0, acc[ch][0], 0, 0, 0);
                acc[ch][1] = __builtin_amdgcn_mfma_f32_16x16x32_bf16(a, b1, acc[ch][1], 0, 0, 0);
                acc[ch][2] = __builtin_amdgcn_mfma_f32_16x16x32_bf16(a, b2, acc[ch][2], 0, 0, 0);
                acc[ch][3] = __builtin_amdgcn_mfma_f32_16x16x32_bf16(a, b3, acc[ch][3], 0, 0, 0);
            }
        }
    }

    #pragma unroll
    for (int ch = 0; ch < NCHMAX; ++ch) {
        if (ch < nch) {
            #pragma unroll
            for (int r = 0; r < 4; ++r) {
                int rg = r0 + ch * 64 + w * 16 + grp * 4 + r;
                if (rg < rows) {
                    int ent2 = slot[e * CAP + rg];
                    float wgt = topw[ent2];
                    float* obase = out + (size_t)(ent2 >> 3) * H_DIM + c0 + l15;
                    #pragma unroll
                    for (int f = 0; f < 4; ++f)
                        atomicAdd(obase + f * 16, wgt * acc[ch][f][r]);
                }
            }
        }
    }
}

extern "C" void kernel_launch(void* const* d_in, const int* in_sizes, int n_in,
                              void* d_out, int out_size, void* d_ws, size_t ws_size,
                              hipStream_t stream) {
    const float* x   = (const float*)d_in[0];
    const float* wr  = (const float*)d_in[1];
    const float* gup = (const float*)d_in[2];
    const float* dwn = (const float*)d_in[3];
    float* out = (float*)d_out;
    char* ws = (char*)d_ws;

    int*            topi = (int*)(ws + 0);         //  64 KB
    float*          topw = (float*)(ws + 65536);   //  64 KB
    int*            cnt  = (int*)(ws + 131072);    // 256 B
    int*            offs = (int*)(ws + 131328);    // 256 B
    int*            slot = (int*)(ws + 131584);    // 256 KB
    unsigned short* hws  = (unsigned short*)(ws + 393728);  // 24 MB
    // total ws usage: ~25.6 MB (proven footprint)

    int n4 = out_size / 4;
    zero_kernel<<<(n4 + 255) / 256, 256, 0, stream>>>(out, n4, cnt);
    router_kernel<<<T_TOKENS, 256, 0, stream>>>(x, wr, topi, topw);
    dispatch_kernel<<<TK / 256, 256, 0, stream>>>(topi, cnt, slot);
    offs_kernel<<<1, 64, 0, stream>>>(cnt, offs);
    gemm_gu_kernel<<<dim3(3, 24, E_NUM), 256, 0, stream>>>(x, gup, slot, cnt, offs, hws);
    gemm_down_kernel<<<dim3(3, 32, E_NUM), 256, 0, stream>>>(hws, dwn, slot, cnt, offs, topw, out);
}

// Round 5
// 1183.416 us; speedup vs baseline: 4.6092x; 1.1928x over previous
//
#include <hip/hip_runtime.h>
#include <math.h>

#define T_TOKENS 2048
#define H_DIM 2048
#define E_NUM 64
#define I_DIM 768
#define TOPK 8
#define CAP 1024
#define TK (T_TOKENS * TOPK)
#define RCH 384   // rows per super-chunk (6 x 64)
#define NCHMAX 6

typedef __attribute__((ext_vector_type(8))) short s8v;
typedef __attribute__((ext_vector_type(4))) float f32x4;

__device__ inline unsigned short f2bf(float f) {
    union { float f; unsigned int u; } v; v.f = f;
    return (unsigned short)((v.u + 0x7FFFu + ((v.u >> 16) & 1u)) >> 16);
}
// packed RNE f32->bf16x2 (single VALU instruction)
__device__ inline unsigned int pack2(float lo, float hi) {
    unsigned int r;
    asm("v_cvt_pk_bf16_f32 %0, %1, %2" : "=v"(r) : "v"(lo), "v"(hi));
    return r;
}

// ---------------- zero output + counts ----------------
__global__ __launch_bounds__(256) void zero_kernel(float* __restrict__ out, int n4, int* __restrict__ cnt) {
    int i = blockIdx.x * 256 + threadIdx.x;
    if (i < n4) reinterpret_cast<float4*>(out)[i] = make_float4(0.f, 0.f, 0.f, 0.f);
    if (blockIdx.x == 0 && threadIdx.x < E_NUM) cnt[threadIdx.x] = 0;
}

// ---------------- router (proven) ----------------
__global__ __launch_bounds__(256) void router_kernel(const float* __restrict__ x,
                                                     const float* __restrict__ wr,
                                                     int* __restrict__ topi,
                                                     float* __restrict__ topw) {
    __shared__ float xs[H_DIM];
    __shared__ float lg[E_NUM];
    int t = blockIdx.x;
    int tid = threadIdx.x;
    const float* xrow = x + (size_t)t * H_DIM;
    {
        int i = tid * 8;
        *reinterpret_cast<float4*>(xs + i)     = *reinterpret_cast<const float4*>(xrow + i);
        *reinterpret_cast<float4*>(xs + i + 4) = *reinterpret_cast<const float4*>(xrow + i + 4);
    }
    __syncthreads();
    int w = tid >> 6, lane = tid & 63;
    for (int eo = 0; eo < 16; ++eo) {
        int e = w * 16 + eo;
        const float* wrow = wr + (size_t)e * H_DIM;
        float p = 0.f;
        for (int h = lane; h < H_DIM; h += 64) p += xs[h] * wrow[h];
        #pragma unroll
        for (int off = 32; off; off >>= 1) p += __shfl_xor(p, off);
        if (lane == 0) lg[e] = p;
    }
    __syncthreads();
    if (tid < TOPK) {
        float pv = 3.4e38f; int pi = -1;
        float m = 0.f, s = 0.f, myv = 0.f; int myi = 0;
        for (int r = 0; r < TOPK; ++r) {
            float best = -3.4e38f; int bi = -1;
            for (int e2 = 0; e2 < E_NUM; ++e2) {
                float v = lg[e2];
                bool excl = (v > pv) || (v == pv && e2 <= pi);
                if (!excl && v > best) { best = v; bi = e2; }
            }
            if (r == 0) m = best;
            s += expf(best - m);
            if (r == tid) { myv = best; myi = bi; }
            pv = best; pi = bi;
        }
        topw[t * TOPK + tid] = expf(myv - m) / s;
        topi[t * TOPK + tid] = myi;
    }
}

// ---------------- dispatch entries to expert slots ----------------
__global__ __launch_bounds__(256) void dispatch_kernel(const int* __restrict__ topi,
                                                       int* __restrict__ cnt,
                                                       int* __restrict__ slot) {
    int i = blockIdx.x * 256 + threadIdx.x;
    int e = topi[i];
    int pos = atomicAdd(cnt + e, 1);
    if (pos < CAP) slot[e * CAP + pos] = i;
}

// ---------------- exclusive prefix of clamped counts ----------------
__global__ void offs_kernel(const int* __restrict__ cnt, int* __restrict__ offs) {
    if (threadIdx.x == 0) {
        int run = 0;
        for (int e = 0; e < E_NUM; ++e) {
            offs[e] = run;
            int c = cnt[e]; if (c > CAP) c = CAP;
            run += c;
        }
    }
}

// ---------------- GEMM A (MFMA, 2-phase pipelined): h = silu(x@Wg)*(x@Wu) -> bf16 ws --------
__global__ __launch_bounds__(256, 2) void gemm_gu_kernel(const float* __restrict__ x,
                                                         const float* __restrict__ gup,
                                                         const int* __restrict__ slot,
                                                         const int* __restrict__ cnt,
                                                         const int* __restrict__ offs,
                                                         unsigned short* __restrict__ hws) {
    int e = blockIdx.z;
    int rows = min(cnt[e], CAP);
    int r0 = blockIdx.x * RCH;
    if (r0 >= rows) return;
    int nch = min(NCHMAX, (rows - r0 + 63) >> 6);
    int c0g = blockIdx.y * 32;

    __shared__ unsigned short As[RCH][40];  // [row][k32 + pad8]
    __shared__ unsigned short Bt[64][40];   // [colL][k32 + pad8]; L<32 gate, L>=32 up

    int tid = threadIdx.x;
    int w = tid >> 6, lane = tid & 63, grp = lane >> 4, l15 = lane & 15;

    int arow_l = tid >> 2, aq = tid & 3;
    const float* ab[NCHMAX];
    {
        int ent0 = slot[e * CAP + r0];
        #pragma unroll
        for (int p = 0; p < NCHMAX; ++p) {
            int rg = r0 + arow_l + p * 64;
            int ent = (rg < rows) ? slot[e * CAP + rg] : ent0;
            ab[p] = x + (size_t)(ent >> 3) * H_DIM + aq * 8;
        }
    }

    int bL = tid & 63, boct = tid >> 6;
    int gcol = (bL < 32) ? (c0g + bL) : (I_DIM + c0g + (bL - 32));
    const float* bbase = gup + ((size_t)e * H_DIM + boct * 8) * (2 * I_DIM) + gcol;

    f32x4 zero4 = {0.f, 0.f, 0.f, 0.f};
    f32x4 acc[NCHMAX][4];
    #pragma unroll
    for (int c = 0; c < NCHMAX; ++c)
        #pragma unroll
        for (int f = 0; f < 4; ++f) acc[c][f] = zero4;

    // prefetch registers
    float pb[8];
    float4 pa0[NCHMAX], pa1[NCHMAX];

    // prologue: issue tile-0 loads
    #pragma unroll
    for (int j = 0; j < 8; ++j) pb[j] = bbase[(size_t)j * (2 * I_DIM)];
    #pragma unroll
    for (int p = 0; p < NCHMAX; ++p) {
        if (p < nch) {
            pa0[p] = *reinterpret_cast<const float4*>(ab[p]);
            pa1[p] = *reinterpret_cast<const float4*>(ab[p] + 4);
        }
    }

    for (int kk = 0; kk < H_DIM; kk += 32) {
        __syncthreads();   // all waves done reading LDS tile t-1
        // pack (waits vmcnt for tile t) + write LDS
        {
            int4 bo;
            bo.x = (int)pack2(pb[0], pb[1]);
            bo.y = (int)pack2(pb[2], pb[3]);
            bo.z = (int)pack2(pb[4], pb[5]);
            bo.w = (int)pack2(pb[6], pb[7]);
            *reinterpret_cast<int4*>(&Bt[bL][boct * 8]) = bo;
        }
        #pragma unroll
        for (int p = 0; p < NCHMAX; ++p) {
            if (p < nch) {
                int4 ao;
                ao.x = (int)pack2(pa0[p].x, pa0[p].y);
                ao.y = (int)pack2(pa0[p].z, pa0[p].w);
                ao.z = (int)pack2(pa1[p].x, pa1[p].y);
                ao.w = (int)pack2(pa1[p].z, pa1[p].w);
                *reinterpret_cast<int4*>(&As[arow_l + p * 64][aq * 8]) = ao;
            }
        }
        __syncthreads();   // tile t visible to all
        // issue tile t+1 loads (overlap with compute below)
        if (kk + 32 < H_DIM) {
            int kn = kk + 32;
            #pragma unroll
            for (int j = 0; j < 8; ++j) pb[j] = bbase[(size_t)(kn + j) * (2 * I_DIM)];
            #pragma unroll
            for (int p = 0; p < NCHMAX; ++p) {
                if (p < nch) {
                    pa0[p] = *reinterpret_cast<const float4*>(ab[p] + kn);
                    pa1[p] = *reinterpret_cast<const float4*>(ab[p] + kn + 4);
                }
            }
        }
        // compute tile t
        s8v b0 = *reinterpret_cast<const s8v*>(&Bt[0 * 16 + l15][grp * 8]);
        s8v b1 = *reinterpret_cast<const s8v*>(&Bt[1 * 16 + l15][grp * 8]);
        s8v b2 = *reinterpret_cast<const s8v*>(&Bt[2 * 16 + l15][grp * 8]);
        s8v b3 = *reinterpret_cast<const s8v*>(&Bt[3 * 16 + l15][grp * 8]);
        #pragma unroll
        for (int ch = 0; ch < NCHMAX; ++ch) {
            if (ch < nch) {
                s8v a = *reinterpret_cast<const s8v*>(&As[ch * 64 + w * 16 + l15][grp * 8]);
                acc[ch][0] = __builtin_amdgcn_mfma_f32_16x16x32_bf16(a, b0, acc[ch][0], 0, 0, 0);
                acc[ch][1] = __builtin_amdgcn_mfma_f32_16x16x32_bf16(a, b1, acc[ch][1], 0, 0, 0);
                acc[ch][2] = __builtin_amdgcn_mfma_f32_16x16x32_bf16(a, b2, acc[ch][2], 0, 0, 0);
                acc[ch][3] = __builtin_amdgcn_mfma_f32_16x16x32_bf16(a, b3, acc[ch][3], 0, 0, 0);
            }
        }
    }

    int off_e = offs[e];
    #pragma unroll
    for (int ch = 0; ch < NCHMAX; ++ch) {
        if (ch < nch) {
            #pragma unroll
            for (int f = 0; f < 2; ++f) {
                #pragma unroll
                for (int r = 0; r < 4; ++r) {
                    int rg = r0 + ch * 64 + w * 16 + grp * 4 + r;
                    if (rg < rows) {
                        float g = acc[ch][f][r];
                        float u = acc[ch][f + 2][r];
                        float hv = (g / (1.f + expf(-g))) * u;
                        hws[(size_t)(off_e + rg) * I_DIM + (c0g + f * 16 + l15)] = f2bf(hv);
                    }
                }
            }
        }
    }
}

// ---------------- GEMM B (MFMA, 2-phase pipelined): y += w * (h @ Wd), scatter-add ----------
__global__ __launch_bounds__(256, 2) void gemm_down_kernel(const unsigned short* __restrict__ hws,
                                                           const float* __restrict__ dwn,
                                                           const int* __restrict__ slot,
                                                           const int* __restrict__ cnt,
                                                           const int* __restrict__ offs,
                                                           const float* __restrict__ topw,
                                                           float* __restrict__ out) {
    int e = blockIdx.z;
    int rows = min(cnt[e], CAP);
    int r0 = blockIdx.x * RCH;
    if (r0 >= rows) return;
    int nch = min(NCHMAX, (rows - r0 + 63) >> 6);
    int c0 = blockIdx.y * 64;
    int off_e = offs[e];

    __shared__ unsigned short As[RCH][40];
    __shared__ unsigned short Bt[64][40];

    int tid = threadIdx.x;
    int w = tid >> 6, lane = tid & 63, grp = lane >> 4, l15 = lane & 15;

    int arow_l = tid >> 2, aq = tid & 3;
    const unsigned short* ab[NCHMAX];
    #pragma unroll
    for (int p = 0; p < NCHMAX; ++p) {
        int rg = r0 + arow_l + p * 64;
        int rc = (rg < rows) ? rg : r0;
        ab[p] = hws + (size_t)(off_e + rc) * I_DIM + aq * 8;
    }

    int bL = tid & 63, boct = tid >> 6;
    const float* bbase = dwn + ((size_t)e * I_DIM + boct * 8) * H_DIM + c0 + bL;

    f32x4 zero4 = {0.f, 0.f, 0.f, 0.f};
    f32x4 acc[NCHMAX][4];
    #pragma unroll
    for (int c = 0; c < NCHMAX; ++c)
        #pragma unroll
        for (int f = 0; f < 4; ++f) acc[c][f] = zero4;

    float pb[8];
    int4 pa[NCHMAX];

    #pragma unroll
    for (int j = 0; j < 8; ++j) pb[j] = bbase[(size_t)j * H_DIM];
    #pragma unroll
    for (int p = 0; p < NCHMAX; ++p)
        if (p < nch) pa[p] = *reinterpret_cast<const int4*>(ab[p]);

    for (int kk = 0; kk < I_DIM; kk += 32) {
        __syncthreads();
        {
            int4 bo;
            bo.x = (int)pack2(pb[0], pb[1]);
            bo.y = (int)pack2(pb[2], pb[3]);
            bo.z = (int)pack2(pb[4], pb[5]);
            bo.w = (int)pack2(pb[6], pb[7]);
            *reinterpret_cast<int4*>(&Bt[bL][boct * 8]) = bo;
        }
        #pragma unroll
        for (int p = 0; p < NCHMAX; ++p)
            if (p < nch) *reinterpret_cast<int4*>(&As[arow_l + p * 64][aq * 8]) = pa[p];
        __syncthreads();
        if (kk + 32 < I_DIM) {
            int kn = kk + 32;
            #pragma unroll
            for (int j = 0; j < 8; ++j) pb[j] = bbase[(size_t)(kn + j) * H_DIM];
            #pragma unroll
            for (int p = 0; p < NCHMAX; ++p)
                if (p < nch) pa[p] = *reinterpret_cast<const int4*>(ab[p] + kn);
        }
        s8v b0 = *reinterpret_cast<const s8v*>(&Bt[0 * 16 + l15][grp * 8]);
        s8v b1 = *reinterpret_cast<const s8v*>(&Bt[1 * 16 + l15][grp * 8]);
        s8v b2 = *reinterpret_cast<const s8v*>(&Bt[2 * 16 + l15][grp * 8]);
        s8v b3 = *reinterpret_cast<const s8v*>(&Bt[3 * 16 + l15][grp * 8]);
        #pragma unroll
        for (int ch = 0; ch < NCHMAX; ++ch) {
            if (ch < nch) {
                s8v a = *reinterpret_cast<const s8v*>(&As[ch * 64 + w * 16 + l15][grp * 8]);
                acc[ch][0] = __builtin_amdgcn_mfma_f32_16x16x32_bf16(a, b0, acc[ch][0], 0, 0, 0);
                acc[ch][1] = __builtin_amdgcn_mfma_f32_16x16x32_bf16(a, b1, acc[ch][1], 0, 0, 0);
                acc[ch][2] = __builtin_amdgcn_mfma_f32_16x16x32_bf16(a, b2, acc[ch][2], 0, 0, 0);
                acc[ch][3] = __builtin_amdgcn_mfma_f32_16x16x32_bf16(a, b3, acc[ch][3], 0, 0, 0);
            }
        }
    }

    #pragma unroll
    for (int ch = 0; ch < NCHMAX; ++ch) {
        if (ch < nch) {
            #pragma unroll
            for (int r = 0; r < 4; ++r) {
                int rg = r0 + ch * 64 + w * 16 + grp * 4 + r;
                if (rg < rows) {
                    int ent2 = slot[e * CAP + rg];
                    float wgt = topw[ent2];
                    float* obase = out + (size_t)(ent2 >> 3) * H_DIM + c0 + l15;
                    #pragma unroll
                    for (int f = 0; f < 4; ++f)
                        atomicAdd(obase + f * 16, wgt * acc[ch][f][r]);
                }
            }
        }
    }
}

extern "C" void kernel_launch(void* const* d_in, const int* in_sizes, int n_in,
                              void* d_out, int out_size, void* d_ws, size_t ws_size,
                              hipStream_t stream) {
    const float* x   = (const float*)d_in[0];
    const float* wr  = (const float*)d_in[1];
    const float* gup = (const float*)d_in[2];
    const float* dwn = (const float*)d_in[3];
    float* out = (float*)d_out;
    char* ws = (char*)d_ws;

    int*            topi = (int*)(ws + 0);         //  64 KB
    float*          topw = (float*)(ws + 65536);   //  64 KB
    int*            cnt  = (int*)(ws + 131072);    // 256 B
    int*            offs = (int*)(ws + 131328);    // 256 B
    int*            slot = (int*)(ws + 131584);    // 256 KB
    unsigned short* hws  = (unsigned short*)(ws + 393728);  // 24 MB
    // total ws usage: ~25.6 MB (proven footprint)

    int n4 = out_size / 4;
    zero_kernel<<<(n4 + 255) / 256, 256, 0, stream>>>(out, n4, cnt);
    router_kernel<<<T_TOKENS, 256, 0, stream>>>(x, wr, topi, topw);
    dispatch_kernel<<<TK / 256, 256, 0, stream>>>(topi, cnt, slot);
    offs_kernel<<<1, 64, 0, stream>>>(cnt, offs);
    gemm_gu_kernel<<<dim3(3, 24, E_NUM), 256, 0, stream>>>(x, gup, slot, cnt, offs, hws);
    gemm_down_kernel<<<dim3(3, 32, E_NUM), 256, 0, stream>>>(hws, dwn, slot, cnt, offs, topw, out);
}